// Round 6
// baseline (220.333 us; speedup 1.0000x reference)
//
#include <hip/hip_runtime.h>
#include <math.h>

#define D 4096
#define E_EXPERTS 64
#define NTOK 32768
#define BM 64
#define NTHREADS 256
#define NKT 128          /* K-steps of 32 */
#define L_LD 65
#define SMEM_FLOATS 4608 /* epilogue only */
#define TAU 2.5e-4f
#define WP_OFF 4096      /* byte offset of W_prep inside ws */
#define WPLANE 524288    /* bytes per plane (hi, lo) */

// out layout (float32):
//   [0,65536) indices, [65536,131072) weights,
//   [131072] balance_loss, [131073] z_loss, [131074,131138) tokens_per_expert
// ws: [0,64) counts, [64,128) prob sums, [128] lse sum; W_prep at +4096 B

typedef float f32x4 __attribute__((ext_vector_type(4)));
typedef short short8v __attribute__((ext_vector_type(8)));

__device__ __forceinline__ unsigned short f2bf_rne(float f) {
  unsigned u = __builtin_bit_cast(unsigned, f);
  unsigned r = (u + 0x7fffu + ((u >> 16) & 1u)) >> 16;
  return (unsigned short)r;
}
__device__ __forceinline__ float bf2f(unsigned short h) {
  unsigned u = ((unsigned)h) << 16;
  return __builtin_bit_cast(float, u);
}

__device__ __forceinline__ void split8(float4 a, float4 b, short8v* h,
                                       short8v* l) {
  float f[8] = {a.x, a.y, a.z, a.w, b.x, b.y, b.z, b.w};
  short8v hv, lv;
#pragma unroll
  for (int i = 0; i < 8; ++i) {
    unsigned short hs = f2bf_rne(f[i]);
    float rem = f[i] - bf2f(hs);
    hv[i] = (short)hs;
    lv[i] = (short)f2bf_rne(rem);
  }
  *h = hv;
  *l = lv;
}

// ---- prologue: gate_w (fp32) -> bf16 hi/lo planes, pre-swizzled per K-tile:
// plane layout: [kt][t = oct*64 + e][8 bf16] -> byte offset kt*4096 + t*16.
__global__ __launch_bounds__(256)
void prep_w(const float* __restrict__ gw, unsigned short* __restrict__ wph) {
  unsigned short* wpl = wph + (WPLANE / 2);
  int i = blockIdx.x * 256 + threadIdx.x;  // 65536 threads, 1 float4 each
  int e = i >> 10;
  int k = (i & 1023) << 2;
  float4 v = *(const float4*)(gw + (size_t)e * D + k);
  float f[4] = {v.x, v.y, v.z, v.w};
  int kt = k >> 5, oct = (k >> 3) & 3, k8 = k & 7;
  size_t base = (size_t)kt * 2048 + (size_t)(oct * 64 + e) * 8 + k8;
  unsigned long long ph = 0ull, pl = 0ull;
#pragma unroll
  for (int j = 0; j < 4; ++j) {
    unsigned short hs = f2bf_rne(f[j]);
    unsigned short ls = f2bf_rne(f[j] - bf2f(hs));
    ph |= (unsigned long long)hs << (16 * j);
    pl |= (unsigned long long)ls << (16 * j);
  }
  *(unsigned long long*)(wph + base) = ph;
  *(unsigned long long*)(wpl + base) = pl;
}

__global__ __launch_bounds__(NTHREADS)
void moe_router_main(const float* __restrict__ x,
                     const float* __restrict__ gw,
                     const char* __restrict__ wp,  // W_prep base (hi plane)
                     float* __restrict__ out, float* __restrict__ ws) {
  __shared__ __align__(16) float smem[SMEM_FLOATS];

  const int tid = threadIdx.x;
  const int bid = blockIdx.x;
  const int t0 = bid * BM;
  const int w = tid >> 6;  // wave 0..3 owns tokens [w*16, w*16+16)
  const int l = tid & 63;
  const int c4 = l >> 4, rb = l & 15;

  // A: lane (c4, rb) holds token row w*16+rb, k = kt*32 + c4*8 .. +7
  const size_t aOff = ((size_t)(t0 + w * 16 + rb)) * D + c4 * 8;
  // B fragment byte offsets within a wp K-tile (4096 B): [oct=c4][expert][16B]
  int boff[4];
#pragma unroll
  for (int n = 0; n < 4; ++n) boff[n] = c4 * 1024 + (n * 16 + rb) * 16;

  const char* wpl = wp + WPLANE;

  f32x4 acc[4];
#pragma unroll
  for (int n = 0; n < 4; ++n) acc[n] = (f32x4){0.f, 0.f, 0.f, 0.f};

#define LOAD_A(PA, kt)                                 \
  {                                                    \
    PA[0] = *(const float4*)(x + aOff + (kt)*32);      \
    PA[1] = *(const float4*)(x + aOff + (kt)*32 + 4);  \
  }
#define LOAD_B(BH, BL, kt)                                                    \
  {                                                                           \
    const char* tb_ = wp + (size_t)(kt)*4096;                                 \
    const char* tl_ = wpl + (size_t)(kt)*4096;                                \
    _Pragma("unroll") for (int n = 0; n < 4; ++n) {                           \
      BH[n] = *(const short8v*)(tb_ + boff[n]);                               \
      BL[n] = *(const short8v*)(tl_ + boff[n]);                               \
    }                                                                         \
  }
#define COMPUTE_SET(PA, BH, BL)                                                \
  {                                                                            \
    short8v ah, al;                                                            \
    split8(PA[0], PA[1], &ah, &al);                                            \
    _Pragma("unroll") for (int n = 0; n < 4; ++n) {                            \
      acc[n] =                                                                 \
          __builtin_amdgcn_mfma_f32_16x16x32_bf16(ah, BH[n], acc[n], 0, 0, 0); \
      acc[n] =                                                                 \
          __builtin_amdgcn_mfma_f32_16x16x32_bf16(ah, BL[n], acc[n], 0, 0, 0); \
      acc[n] =                                                                 \
          __builtin_amdgcn_mfma_f32_16x16x32_bf16(al, BH[n], acc[n], 0, 0, 0); \
    }                                                                          \
  }

  // two named register sets, refill-after-consume (no LDS, no barriers)
  float4 pa0[2], pa1[2];
  short8v bh0[4], bl0[4], bh1[4], bl1[4];
  LOAD_A(pa0, 0);
  LOAD_B(bh0, bl0, 0);
  LOAD_A(pa1, 1);
  LOAD_B(bh1, bl1, 1);

  for (int kt = 0; kt < NKT; kt += 2) {
    COMPUTE_SET(pa0, bh0, bl0);
    if (kt + 2 < NKT) {
      LOAD_A(pa0, kt + 2);
      LOAD_B(bh0, bl0, kt + 2);
    }
    COMPUTE_SET(pa1, bh1, bl1);
    if (kt + 3 < NKT) {
      LOAD_A(pa1, kt + 3);
      LOAD_B(bh1, bl1, kt + 3);
    }
  }

  // ---- epilogue: logits -> LDS L[64][65] ----
  // D layout (verified R4/R5): col = lane&15, row_in_wave = (lane>>4)*4 + reg
#pragma unroll
  for (int n = 0; n < 4; ++n)
#pragma unroll
    for (int r = 0; r < 4; ++r) {
      int row = w * 16 + c4 * 4 + r;
      int col = n * 16 + rb;
      smem[row * L_LD + col] = acc[n][r];
    }

  float* L = smem;                  // [64][65]
  float* mArr = smem + BM * L_LD;   // [64]
  float* zArr = mArr + BM;          // [64] 1/Z
  float* cntL = zArr + BM;          // [64]
  float* probA = cntL + E_EXPERTS;  // [64]
  if (tid < E_EXPERTS) {
    cntL[tid] = 0.0f;
    probA[tid] = 0.0f;
  }
  __syncthreads();

  if (tid < BM) {  // exactly wave 0
    const int lane = tid;
    const float* row = L + tid * L_LD;
    float m1 = -3.4e38f, m2 = -3.4e38f, m3 = -3.4e38f;
    int i1 = 0, i2 = 0, i3 = 0;
    for (int e = 0; e < E_EXPERTS; ++e) {
      float v = row[e];
      if (v > m1) {
        m3 = m2; i3 = i2;
        m2 = m1; i2 = i1;
        m1 = v;  i1 = e;
      } else if (v > m2) {
        m3 = m2; i3 = i2;
        m2 = v;  i2 = e;
      } else if (v > m3) {
        m3 = v; i3 = e;
      }
    }
    float z = 0.0f;
    for (int e = 0; e < E_EXPERTS; ++e) z += __expf(row[e] - m1);
    mArr[tid] = m1;
    zArr[tid] = 1.0f / z;
    float lseVal = m1 + logf(z);

    // ---- fp64 refinement of near-ties (rare, ~70 tokens grid-wide) ----
    bool risky = (m1 - m2 < TAU) || (m2 - m3 < TAU);
    double r1 = 0.0, r2 = 0.0, r3 = 0.0;
    unsigned long long mask = __ballot(risky);
    while (mask) {
      int src = __ffsll((long long)mask) - 1;
      mask &= (mask - 1);
      int tok = t0 + src;
      int j1 = __shfl(i1, src, 64);
      int j2 = __shfl(i2, src, 64);
      int j3 = __shfl(i3, src, 64);
      const float* xr = x + (size_t)tok * D;
      const float* g1 = gw + (size_t)j1 * D;
      const float* g2 = gw + (size_t)j2 * D;
      const float* g3 = gw + (size_t)j3 * D;
      double a1 = 0.0, a2 = 0.0, a3 = 0.0;
      for (int k = lane * 4; k < D; k += 256) {
        float4 xv = *(const float4*)(xr + k);
        float4 w1 = *(const float4*)(g1 + k);
        float4 w2 = *(const float4*)(g2 + k);
        float4 w3 = *(const float4*)(g3 + k);
        a1 += (double)xv.x * w1.x + (double)xv.y * w1.y +
              (double)xv.z * w1.z + (double)xv.w * w1.w;
        a2 += (double)xv.x * w2.x + (double)xv.y * w2.y +
              (double)xv.z * w2.z + (double)xv.w * w2.w;
        a3 += (double)xv.x * w3.x + (double)xv.y * w3.y +
              (double)xv.z * w3.z + (double)xv.w * w3.w;
      }
#pragma unroll
      for (int off = 32; off > 0; off >>= 1) {
        a1 += __shfl_down(a1, off, 64);
        a2 += __shfl_down(a2, off, 64);
        a3 += __shfl_down(a3, off, 64);
      }
      a1 = __shfl(a1, 0, 64);
      a2 = __shfl(a2, 0, 64);
      a3 = __shfl(a3, 0, 64);
      if (lane == src) { r1 = a1; r2 = a2; r3 = a3; }
    }

    float wOut1, wOut2;
    if (risky) {
      double v[3] = {r1, r2, r3};
      int ix[3] = {i1, i2, i3};
#define SORT_SWAP(a, b)                                            \
      if (v[b] > v[a] || (v[b] == v[a] && ix[b] < ix[a])) {        \
        double tv = v[a]; v[a] = v[b]; v[b] = tv;                  \
        int ti = ix[a]; ix[a] = ix[b]; ix[b] = ti;                 \
      }
      SORT_SWAP(0, 1);
      SORT_SWAP(1, 2);
      SORT_SWAP(0, 1);
#undef SORT_SWAP
      i1 = ix[0]; i2 = ix[1];
      double d = exp(v[1] - v[0]);
      wOut1 = (float)(1.0 / (1.0 + d));
      wOut2 = (float)(d / (1.0 + d));
    } else {
      float e2 = __expf(m2 - m1);
      wOut1 = 1.0f / (1.0f + e2);
      wOut2 = e2 * wOut1;
    }

    size_t ot = ((size_t)t0 + tid) * 2;
    out[ot] = (float)i1;
    out[ot + 1] = (float)i2;
    out[(size_t)NTOK * 2 + ot] = wOut1;
    out[(size_t)NTOK * 2 + ot + 1] = wOut2;

    atomicAdd(&cntL[i1], 1.0f);
    atomicAdd(&cntL[i2], 1.0f);

    float v = lseVal;
#pragma unroll
    for (int off = 32; off > 0; off >>= 1) v += __shfl_down(v, off, 64);
    if (tid == 0) atomicAdd(&ws[128], v);
  }
  __syncthreads();
  if (tid < E_EXPERTS) atomicAdd(&ws[tid], cntL[tid]);

  // per-expert prob sums: thread (e, q) sums 16 tokens
  {
    const int e = tid & 63;
    const int q = tid >> 6;
    float s = 0.0f;
    for (int t = q * 16; t < q * 16 + 16; ++t)
      s += __expf(L[t * L_LD + e] - mArr[t]) * zArr[t];
    atomicAdd(&probA[e], s);
  }
  __syncthreads();
  if (tid < E_EXPERTS) atomicAdd(&ws[64 + tid], probA[tid]);
}

__global__ void moe_finalize(const float* __restrict__ ws,
                             float* __restrict__ out) {
  const int e = threadIdx.x;  // 64 threads
  const float inv_n = 1.0f / (float)NTOK;
  float tpe = ws[e] * inv_n;
  out[131074 + e] = tpe;
  float rppe = ws[64 + e] * inv_n;
  float part = tpe * rppe;
#pragma unroll
  for (int off = 32; off > 0; off >>= 1) part += __shfl_down(part, off, 64);
  if (e == 0) {
    out[131072] = part * 64.0f * 0.01f;
    float meanLse = ws[128] * inv_n;
    out[131073] = meanLse * meanLse * 0.001f;
  }
}

extern "C" void kernel_launch(void* const* d_in, const int* in_sizes, int n_in,
                              void* d_out, int out_size, void* d_ws, size_t ws_size,
                              hipStream_t stream) {
  const float* x = (const float*)d_in[0];
  const float* gw = (const float*)d_in[1];
  float* out = (float*)d_out;
  float* ws = (float*)d_ws;
  unsigned short* wph = (unsigned short*)((char*)d_ws + WP_OFF);

  hipMemsetAsync(d_ws, 0, 129 * sizeof(float), stream);
  hipLaunchKernelGGL(prep_w, dim3(256), dim3(256), 0, stream, gw, wph);
  hipLaunchKernelGGL(moe_router_main, dim3(NTOK / BM), dim3(NTHREADS), 0, stream,
                     x, gw, (const char*)wph, out, ws);
  hipLaunchKernelGGL(moe_finalize, dim3(1), dim3(E_EXPERTS), 0, stream, ws, out);
}

// Round 7
// 161.577 us; speedup vs baseline: 1.3636x; 1.3636x over previous
//
#include <hip/hip_runtime.h>
#include <math.h>

#define D 4096
#define E_EXPERTS 64
#define NTOK 32768
#define BM 64            /* tokens per block */
#define NTHREADS 256
#define WKT 32           /* K-steps of 32 per wave (K/4/32) */
#define L_LD 65
#define LREG 4160        /* floats per wave partial region (64*65) */
#define SMEM_FLOATS 16896
#define TAU 2.5e-4f
#define WP_OFF 4096      /* byte offset of W_prep inside ws */
#define WPLANE 524288    /* bytes per plane (hi, lo) */

// out layout (float32):
//   [0,65536) indices, [65536,131072) weights,
//   [131072] balance_loss, [131073] z_loss, [131074,131138) tokens_per_expert
// ws: [0,64) counts, [64,128) prob sums, [128] lse sum; W_prep at +4096 B

typedef float f32x4 __attribute__((ext_vector_type(4)));
typedef short short8v __attribute__((ext_vector_type(8)));

__device__ __forceinline__ unsigned short f2bf_rne(float f) {
  unsigned u = __builtin_bit_cast(unsigned, f);
  unsigned r = (u + 0x7fffu + ((u >> 16) & 1u)) >> 16;
  return (unsigned short)r;
}
__device__ __forceinline__ float bf2f(unsigned short h) {
  unsigned u = ((unsigned)h) << 16;
  return __builtin_bit_cast(float, u);
}

__device__ __forceinline__ void split8(float4 a, float4 b, short8v* h,
                                       short8v* l) {
  float f[8] = {a.x, a.y, a.z, a.w, b.x, b.y, b.z, b.w};
  short8v hv, lv;
#pragma unroll
  for (int i = 0; i < 8; ++i) {
    unsigned short hs = f2bf_rne(f[i]);
    float rem = f[i] - bf2f(hs);
    hv[i] = (short)hs;
    lv[i] = (short)f2bf_rne(rem);
  }
  *h = hv;
  *l = lv;
}

// ---- prologue: gate_w (fp32) -> bf16 hi/lo planes, pre-swizzled per K-tile:
// plane layout: [kt][t = oct*64 + e][8 bf16] -> byte offset kt*4096 + t*16.
__global__ __launch_bounds__(256)
void prep_w(const float* __restrict__ gw, unsigned short* __restrict__ wph) {
  unsigned short* wpl = wph + (WPLANE / 2);
  int i = blockIdx.x * 256 + threadIdx.x;  // 65536 threads, 1 float4 each
  int e = i >> 10;
  int k = (i & 1023) << 2;
  float4 v = *(const float4*)(gw + (size_t)e * D + k);
  float f[4] = {v.x, v.y, v.z, v.w};
  int kt = k >> 5, oct = (k >> 3) & 3, k8 = k & 7;
  size_t base = (size_t)kt * 2048 + (size_t)(oct * 64 + e) * 8 + k8;
  unsigned long long ph = 0ull, pl = 0ull;
#pragma unroll
  for (int j = 0; j < 4; ++j) {
    unsigned short hs = f2bf_rne(f[j]);
    unsigned short ls = f2bf_rne(f[j] - bf2f(hs));
    ph |= (unsigned long long)hs << (16 * j);
    pl |= (unsigned long long)ls << (16 * j);
  }
  *(unsigned long long*)(wph + base) = ph;
  *(unsigned long long*)(wpl + base) = pl;
}

__global__ __launch_bounds__(NTHREADS, 2)
void moe_router_main(const float* __restrict__ x,
                     const float* __restrict__ gw,
                     const char* __restrict__ wp,  // W_prep base (hi plane)
                     float* __restrict__ out, float* __restrict__ ws) {
  __shared__ __align__(16) float smem[SMEM_FLOATS];

  const int tid = threadIdx.x;
  const int bid = blockIdx.x;
  const int t0 = bid * BM;
  const int w = tid >> 6;  // wave w owns K-quarter [w*1024, (w+1)*1024)
  const int l = tid & 63;
  const int c4 = l >> 4, rb = l & 15;

  // A: lane (c4, rb), M-frag m -> token t0+m*16+rb, k = w*1024 + kt*32 + c4*8
  size_t aBase[4];
#pragma unroll
  for (int m = 0; m < 4; ++m)
    aBase[m] = ((size_t)(t0 + m * 16 + rb)) * D + w * 1024 + c4 * 8;
  // B fragment byte offsets within a wp K-tile (4096 B): [oct=c4][expert][16B]
  int boff[4];
#pragma unroll
  for (int n = 0; n < 4; ++n) boff[n] = c4 * 1024 + (n * 16 + rb) * 16;

  const char* wpw = wp + (size_t)w * WKT * 4096;           // hi plane, my quarter
  const char* wplw = wp + WPLANE + (size_t)w * WKT * 4096; // lo plane

  f32x4 acc[4][4];
#pragma unroll
  for (int m = 0; m < 4; ++m)
#pragma unroll
    for (int n = 0; n < 4; ++n) acc[m][n] = (f32x4){0.f, 0.f, 0.f, 0.f};

#define LOAD_A(PA, kt)                                            \
  {                                                               \
    _Pragma("unroll") for (int m = 0; m < 4; ++m) {               \
      PA[2 * m] = *(const float4*)(x + aBase[m] + (kt)*32);       \
      PA[2 * m + 1] = *(const float4*)(x + aBase[m] + (kt)*32 + 4); \
    }                                                             \
  }
#define LOAD_B(BH, BL, kt)                                        \
  {                                                               \
    const char* tb_ = wpw + (size_t)(kt)*4096;                    \
    const char* tl_ = wplw + (size_t)(kt)*4096;                   \
    _Pragma("unroll") for (int n = 0; n < 4; ++n) {               \
      BH[n] = *(const short8v*)(tb_ + boff[n]);                   \
      BL[n] = *(const short8v*)(tl_ + boff[n]);                   \
    }                                                             \
  }
#define COMPUTE_SET(PA, BH, BL)                                                \
  {                                                                            \
    _Pragma("unroll") for (int m = 0; m < 4; ++m) {                            \
      short8v ah, al;                                                          \
      split8(PA[2 * m], PA[2 * m + 1], &ah, &al);                              \
      _Pragma("unroll") for (int n = 0; n < 4; ++n) {                          \
        acc[m][n] = __builtin_amdgcn_mfma_f32_16x16x32_bf16(ah, BH[n],         \
                                                            acc[m][n], 0, 0, 0); \
        acc[m][n] = __builtin_amdgcn_mfma_f32_16x16x32_bf16(ah, BL[n],         \
                                                            acc[m][n], 0, 0, 0); \
        acc[m][n] = __builtin_amdgcn_mfma_f32_16x16x32_bf16(al, BH[n],         \
                                                            acc[m][n], 0, 0, 0); \
      }                                                                        \
    }                                                                          \
  }

  // two named register sets, refill-after-consume; no barriers in main loop
  float4 pa0[8], pa1[8];
  short8v bh0[4], bl0[4], bh1[4], bl1[4];
  LOAD_A(pa0, 0);
  LOAD_B(bh0, bl0, 0);
  LOAD_A(pa1, 1);
  LOAD_B(bh1, bl1, 1);

  for (int kt = 0; kt < WKT; kt += 2) {
    COMPUTE_SET(pa0, bh0, bl0);
    if (kt + 2 < WKT) {
      LOAD_A(pa0, kt + 2);
      LOAD_B(bh0, bl0, kt + 2);
    }
    COMPUTE_SET(pa1, bh1, bl1);
    if (kt + 3 < WKT) {
      LOAD_A(pa1, kt + 3);
      LOAD_B(bh1, bl1, kt + 3);
    }
  }

  // ---- epilogue: write per-wave partials, reduce across waves ----
  // D layout (verified R4/R5): col = lane&15, row_in_frag = (lane>>4)*4 + reg
#pragma unroll
  for (int m = 0; m < 4; ++m)
#pragma unroll
    for (int n = 0; n < 4; ++n)
#pragma unroll
      for (int r = 0; r < 4; ++r) {
        int row = m * 16 + c4 * 4 + r;
        int col = n * 16 + rb;
        smem[w * LREG + row * L_LD + col] = acc[m][n][r];
      }

  float* L = smem;                       // [64][65] after reduce
  float* mArr = smem + 4 * LREG;         // [64]
  float* zArr = mArr + BM;               // [64] 1/Z
  float* cntL = zArr + BM;               // [64]
  float* probA = cntL + E_EXPERTS;       // [64]
  if (tid < E_EXPERTS) {
    cntL[tid] = 0.0f;
    probA[tid] = 0.0f;
  }
  __syncthreads();

  // sum the 4 K-quarter partials into region 0 (each (t,e) owned by 1 thread)
#pragma unroll
  for (int i = 0; i < 16; ++i) {
    int idx = tid + i * 256;
    int t = idx >> 6, e = idx & 63;
    int o = t * L_LD + e;
    smem[o] = smem[o] + smem[LREG + o] + smem[2 * LREG + o] + smem[3 * LREG + o];
  }
  __syncthreads();

  if (tid < BM) {  // exactly wave 0
    const int lane = tid;
    const float* row = L + tid * L_LD;
    float m1 = -3.4e38f, m2 = -3.4e38f, m3 = -3.4e38f;
    int i1 = 0, i2 = 0, i3 = 0;
    for (int e = 0; e < E_EXPERTS; ++e) {
      float v = row[e];
      if (v > m1) {
        m3 = m2; i3 = i2;
        m2 = m1; i2 = i1;
        m1 = v;  i1 = e;
      } else if (v > m2) {
        m3 = m2; i3 = i2;
        m2 = v;  i2 = e;
      } else if (v > m3) {
        m3 = v; i3 = e;
      }
    }
    float z = 0.0f;
    for (int e = 0; e < E_EXPERTS; ++e) z += __expf(row[e] - m1);
    mArr[tid] = m1;
    zArr[tid] = 1.0f / z;
    float lseVal = m1 + logf(z);

    // ---- fp64 refinement of near-ties (rare, ~70 tokens grid-wide) ----
    bool risky = (m1 - m2 < TAU) || (m2 - m3 < TAU);
    double r1 = 0.0, r2 = 0.0, r3 = 0.0;
    unsigned long long mask = __ballot(risky);
    while (mask) {
      int src = __ffsll((long long)mask) - 1;
      mask &= (mask - 1);
      int tok = t0 + src;
      int j1 = __shfl(i1, src, 64);
      int j2 = __shfl(i2, src, 64);
      int j3 = __shfl(i3, src, 64);
      const float* xr = x + (size_t)tok * D;
      const float* g1 = gw + (size_t)j1 * D;
      const float* g2 = gw + (size_t)j2 * D;
      const float* g3 = gw + (size_t)j3 * D;
      double a1 = 0.0, a2 = 0.0, a3 = 0.0;
      for (int k = lane * 4; k < D; k += 256) {
        float4 xv = *(const float4*)(xr + k);
        float4 w1 = *(const float4*)(g1 + k);
        float4 w2 = *(const float4*)(g2 + k);
        float4 w3 = *(const float4*)(g3 + k);
        a1 += (double)xv.x * w1.x + (double)xv.y * w1.y +
              (double)xv.z * w1.z + (double)xv.w * w1.w;
        a2 += (double)xv.x * w2.x + (double)xv.y * w2.y +
              (double)xv.z * w2.z + (double)xv.w * w2.w;
        a3 += (double)xv.x * w3.x + (double)xv.y * w3.y +
              (double)xv.z * w3.z + (double)xv.w * w3.w;
      }
#pragma unroll
      for (int off = 32; off > 0; off >>= 1) {
        a1 += __shfl_down(a1, off, 64);
        a2 += __shfl_down(a2, off, 64);
        a3 += __shfl_down(a3, off, 64);
      }
      a1 = __shfl(a1, 0, 64);
      a2 = __shfl(a2, 0, 64);
      a3 = __shfl(a3, 0, 64);
      if (lane == src) { r1 = a1; r2 = a2; r3 = a3; }
    }

    float wOut1, wOut2;
    if (risky) {
      double v[3] = {r1, r2, r3};
      int ix[3] = {i1, i2, i3};
#define SORT_SWAP(a, b)                                            \
      if (v[b] > v[a] || (v[b] == v[a] && ix[b] < ix[a])) {        \
        double tv = v[a]; v[a] = v[b]; v[b] = tv;                  \
        int ti = ix[a]; ix[a] = ix[b]; ix[b] = ti;                 \
      }
      SORT_SWAP(0, 1);
      SORT_SWAP(1, 2);
      SORT_SWAP(0, 1);
#undef SORT_SWAP
      i1 = ix[0]; i2 = ix[1];
      double d = exp(v[1] - v[0]);
      wOut1 = (float)(1.0 / (1.0 + d));
      wOut2 = (float)(d / (1.0 + d));
    } else {
      float e2 = __expf(m2 - m1);
      wOut1 = 1.0f / (1.0f + e2);
      wOut2 = e2 * wOut1;
    }

    size_t ot = ((size_t)t0 + tid) * 2;
    out[ot] = (float)i1;
    out[ot + 1] = (float)i2;
    out[(size_t)NTOK * 2 + ot] = wOut1;
    out[(size_t)NTOK * 2 + ot + 1] = wOut2;

    atomicAdd(&cntL[i1], 1.0f);
    atomicAdd(&cntL[i2], 1.0f);

    float v = lseVal;
#pragma unroll
    for (int off = 32; off > 0; off >>= 1) v += __shfl_down(v, off, 64);
    if (tid == 0) atomicAdd(&ws[128], v);
  }
  __syncthreads();
  if (tid < E_EXPERTS) atomicAdd(&ws[tid], cntL[tid]);

  // per-expert prob sums: thread (e, q) sums 16 tokens
  {
    const int e = tid & 63;
    const int q = tid >> 6;
    float s = 0.0f;
    for (int t = q * 16; t < q * 16 + 16; ++t)
      s += __expf(L[t * L_LD + e] - mArr[t]) * zArr[t];
    atomicAdd(&probA[e], s);
  }
  __syncthreads();
  if (tid < E_EXPERTS) atomicAdd(&ws[64 + tid], probA[tid]);
}

__global__ void moe_finalize(const float* __restrict__ ws,
                             float* __restrict__ out) {
  const int e = threadIdx.x;  // 64 threads
  const float inv_n = 1.0f / (float)NTOK;
  float tpe = ws[e] * inv_n;
  out[131074 + e] = tpe;
  float rppe = ws[64 + e] * inv_n;
  float part = tpe * rppe;
#pragma unroll
  for (int off = 32; off > 0; off >>= 1) part += __shfl_down(part, off, 64);
  if (e == 0) {
    out[131072] = part * 64.0f * 0.01f;
    float meanLse = ws[128] * inv_n;
    out[131073] = meanLse * meanLse * 0.001f;
  }
}

extern "C" void kernel_launch(void* const* d_in, const int* in_sizes, int n_in,
                              void* d_out, int out_size, void* d_ws, size_t ws_size,
                              hipStream_t stream) {
  const float* x = (const float*)d_in[0];
  const float* gw = (const float*)d_in[1];
  float* out = (float*)d_out;
  float* ws = (float*)d_ws;
  unsigned short* wph = (unsigned short*)((char*)d_ws + WP_OFF);

  hipMemsetAsync(d_ws, 0, 129 * sizeof(float), stream);
  hipLaunchKernelGGL(prep_w, dim3(256), dim3(256), 0, stream, gw, wph);
  hipLaunchKernelGGL(moe_router_main, dim3(NTOK / BM), dim3(NTHREADS), 0, stream,
                     x, gw, (const char*)wph, out, ws);
  hipLaunchKernelGGL(moe_finalize, dim3(1), dim3(E_EXPERTS), 0, stream, ws, out);
}